// Round 8
// baseline (339.371 us; speedup 1.0000x reference)
//
#include <hip/hip_runtime.h>
#include <hip/hip_bf16.h>
#include <hip/hip_fp16.h>
#include <math.h>

#define T_STEPS 512
#define NB      16
#define D_IN    512
#define CG      4096
#define CO      5120
#define LMAX    252
#define NEGF    (-1e30f)
#define SCORES_SZ 41943040LL   // NB * T_STEPS * CO
#define L2E 1.4426950408889634f
#define LN2 0.6931471805599453f
#define STAYT 0.36787944117144233f   // exp(2 - 3) tilted stay factor

typedef __attribute__((ext_vector_type(8))) short bf16x8;
typedef __attribute__((ext_vector_type(4))) float f32x4;

__device__ __forceinline__ float tanh5(float x) {
    x = fminf(fmaxf(x, -15.f), 15.f);
    float e = __expf(2.f * x);
    return 5.f * (e - 1.f) / (e + 1.f);
}
__device__ __forceinline__ unsigned short f2bf(float v) {
    __hip_bfloat16 h = __float2bfloat16(v);
    return *reinterpret_cast<unsigned short*>(&h);
}
__device__ __forceinline__ float h2f(unsigned short s) {
    union { unsigned short u; _Float16 h; } c; c.u = s;
    return (float)c.h;
}
__device__ __forceinline__ unsigned short f2h(float v) {
    union { unsigned short u; _Float16 h; } c; c.h = (_Float16)v;
    return c.u;
}
__device__ __forceinline__ void cvt8(uint4 u, float* g) {
    g[0] = h2f((unsigned short)(u.x & 0xffff)); g[1] = h2f((unsigned short)(u.x >> 16));
    g[2] = h2f((unsigned short)(u.y & 0xffff)); g[3] = h2f((unsigned short)(u.y >> 16));
    g[4] = h2f((unsigned short)(u.z & 0xffff)); g[5] = h2f((unsigned short)(u.z >> 16));
    g[6] = h2f((unsigned short)(u.w & 0xffff)); g[7] = h2f((unsigned short)(u.w >> 16));
}
__device__ __forceinline__ void step_barrier() {
    asm volatile("s_waitcnt lgkmcnt(0)" ::: "memory");
    __builtin_amdgcn_s_barrier();
    asm volatile("" ::: "memory");
}
__device__ __forceinline__ void gll16(const unsigned short* g, unsigned short* l) {
    __builtin_amdgcn_global_load_lds((const __attribute__((address_space(1))) void*)g,
                                     (__attribute__((address_space(3))) void*)l, 16, 0, 0);
}

// ---------------- fp32 -> bf16 conversion (RNE) ----------------
__global__ __launch_bounds__(256) void cvt_bf16_kernel(const float* __restrict__ src,
                                                       unsigned short* __restrict__ dst,
                                                       int n4) {
    int i = blockIdx.x * 256 + threadIdx.x;
    if (i < n4) {
        float4 v = *(reinterpret_cast<const float4*>(src) + i);
        ushort4 o;
        o.x = f2bf(v.x); o.y = f2bf(v.y); o.z = f2bf(v.z); o.w = f2bf(v.w);
        *(reinterpret_cast<ushort4*>(dst) + i) = o;
    }
}

// ---------------- bf16 MFMA GEMM + tanh*5 + blank interleave (+ tilted exp f16 copy) ----------------
template <bool WSE>
__global__ __launch_bounds__(256) void crf_gemm_bf16(
    const unsigned short* __restrict__ A16,
    const unsigned short* __restrict__ W16,
    const float* __restrict__ bias,
    float* __restrict__ out,
    unsigned short* __restrict__ e16)
{
    __shared__ unsigned short As[128 * 64];
    __shared__ unsigned short Bs[128 * 64];
    const int tid  = threadIdx.x;
    const int lane = tid & 63;
    const int wv   = __builtin_amdgcn_readfirstlane(tid >> 6);
    const int wr   = wv >> 1, wc = wv & 1;
    const int m0   = blockIdx.y * 128;
    const int n0   = blockIdx.x * 128;
    const int wbase = tid & 192;

    f32x4 acc[4][4];
    #pragma unroll
    for (int i = 0; i < 4; ++i)
        #pragma unroll
        for (int j = 0; j < 4; ++j) acc[i][j] = (f32x4){0.f, 0.f, 0.f, 0.f};

    const int l15 = lane & 15, lj = lane >> 4, l7 = lane & 7;

    for (int k0 = 0; k0 < D_IN; k0 += 64) {
        __syncthreads();
        #pragma unroll
        for (int i = 0; i < 4; ++i) {
            const int c   = i * 256 + tid;
            const int row = c >> 3;
            const int jg  = (c & 7) ^ (row & 7);
            const unsigned short* ga = A16 + (size_t)(m0 + row) * D_IN + k0 + jg * 8;
            const unsigned short* gb = W16 + (size_t)(n0 + row) * D_IN + k0 + jg * 8;
            gll16(ga, As + (size_t)(i * 256 + wbase) * 8);
            gll16(gb, Bs + (size_t)(i * 256 + wbase) * 8);
        }
        __syncthreads();
        #pragma unroll
        for (int ks = 0; ks < 2; ++ks) {
            bf16x8 af[4], bb[4];
            #pragma unroll
            for (int mi = 0; mi < 4; ++mi) {
                const int row = wr * 64 + mi * 16 + l15;
                const int jsw = (ks * 4 + lj) ^ l7;
                af[mi] = *reinterpret_cast<const bf16x8*>(&As[row * 64 + jsw * 8]);
            }
            #pragma unroll
            for (int ni = 0; ni < 4; ++ni) {
                const int row = wc * 64 + ni * 16 + l15;
                const int jsw = (ks * 4 + lj) ^ l7;
                bb[ni] = *reinterpret_cast<const bf16x8*>(&Bs[row * 64 + jsw * 8]);
            }
            #pragma unroll
            for (int mi = 0; mi < 4; ++mi)
                #pragma unroll
                for (int ni = 0; ni < 4; ++ni)
                    acc[mi][ni] = __builtin_amdgcn_mfma_f32_16x16x32_bf16(
                        af[mi], bb[ni], acc[mi][ni], 0, 0, 0);
        }
    }

    float bv[4];
    #pragma unroll
    for (int ni = 0; ni < 4; ++ni) bv[ni] = bias[n0 + wc * 64 + ni * 16 + l15];

    #pragma unroll
    for (int mi = 0; mi < 4; ++mi) {
        #pragma unroll
        for (int r = 0; r < 4; ++r) {
            const int m = m0 + wr * 64 + mi * 16 + lj * 4 + r;
            float* r1 = out + 16 + (size_t)m * CO;
            #pragma unroll
            for (int ni = 0; ni < 4; ++ni) {
                const int n = n0 + wc * 64 + ni * 16 + l15;
                const float v = tanh5(acc[mi][ni][r] + bv[ni]);
                const int ch = (n >> 2) * 5 + (n & 3) + 1;
                r1[ch] = v;
                r1[ch + SCORES_SZ] = v;
                if ((l15 & 3) == 0) {
                    r1[ch - 1] = 2.0f;
                    r1[ch - 1 + SCORES_SZ] = 2.0f;
                }
                if (WSE) e16[(size_t)m * CG + n] = f2h(__expf(v - 3.0f));
            }
        }
    }
}

// ---------------- CTC move-score pre-gather: G16[n][t][i] = E16 at position-i move channel ----------------
__global__ __launch_bounds__(256) void ctc_gather_kernel(
    const unsigned short* __restrict__ e16,
    const int* __restrict__ ys_pad,
    unsigned short* __restrict__ G16)
{
    const int n  = blockIdx.y;
    const int t0 = blockIdx.x * 32;
    const int q  = threadIdx.x;
    __shared__ int tcl[256];
    tcl[q] = max(ys_pad[n * 256 + q] - 1, 0);
    __syncthreads();
    int mch = 0;
    if (q >= 1 && q < LMAX) {
        const int code = tcl[q] * 256 + tcl[q + 1] * 64 + tcl[q + 2] * 16
                       + tcl[q + 3] * 4 + tcl[q + 4];
        mch = code * 4 + tcl[q - 1];
    }
    const unsigned short* eb = e16 + (size_t)(n * T_STEPS) * CG;
    unsigned short* gb = G16 + ((size_t)n * T_STEPS + t0) * 256;
    for (int dt = 0; dt < 32; ++dt)
        gb[dt * 256 + q] = eb[(size_t)(t0 + dt) * CG + mch];
}

// ---------------- bidirectional fwd/bwd, LDS-ring staged (counted vmcnt, raw barrier) ----------------
// 64 blocks x 256 threads. role: 0=CRF fwd, 1=CRF bwd, 2=CTC fwd, 3=CTC bwd.
// CRF prob-domain (f32 exchange, pow2 renorm: reduce at t%8==0, apply 2-stale at t%8==1).
// Staging: global_load_lds ring, 8 steps ahead, s_waitcnt vmcnt(14) (CRF) / vmcnt(7) (CTC wave0),
// barrier drains LDS only -> loads stay in flight across steps (the round<=7 kernels all
// paid full memory latency per step because the compiler drained vmcnt at each barrier/use).
__global__ __launch_bounds__(256) void fb2_kernel(
    const unsigned short* __restrict__ e16,
    const unsigned short* __restrict__ G16,
    const int* __restrict__ ys_lens,
    float* __restrict__ FA, float* __restrict__ FAe,
    float* __restrict__ FB, float* __restrict__ FBe,
    float* __restrict__ CAL, float* __restrict__ CBE)
{
    __shared__ unsigned char SH[139280];
    const int role = blockIdx.x >> 4;
    const int n = blockIdx.x & 15;
    const int q = threadIdx.x;
    const int w = q >> 6, lane = q & 63;
    if (role < 2) {
        // ---------------- CRF halves (prob domain) ----------------
        unsigned short* ring = (unsigned short*)SH;          // [16][4096]
        float* buf   = (float*)(SH + 131072);                // [2][1024]
        float* wmax4 = (float*)(SH + 131072 + 8192);
        const bool FWD = (role == 0);
        const unsigned short* eb = e16 + (size_t)(n * T_STEPS) * CG;
        float P0 = 1.f, P1 = 1.f, P2 = 1.f, P3 = 1.f, acc = 0.f;
        *(float4*)&buf[4 * q] = make_float4(1.f, 1.f, 1.f, 1.f);

        #define CRF_STAGE(s) {                                                    \
            const int rr = ((s) < 256) ? (s) : 255;                               \
            const int erow = FWD ? rr : (511 - rr);                               \
            const unsigned short* ga = eb + (size_t)erow * CG + (w << 10) + lane * 8; \
            unsigned short* la = ring + (((s) & 15) << 12) + (w << 10);           \
            gll16(ga, la);                                                        \
            gll16(ga + 512, la + 512); }

        #pragma unroll
        for (int s = 0; s < 8; ++s) CRF_STAGE(s);
        asm volatile("s_waitcnt vmcnt(14)" ::: "memory");
        step_barrier();
        int cur = 0;
        for (int t = 0; t < 256; ++t) {
            CRF_STAGE(t + 8);
            const unsigned short* rg = ring + ((t & 15) << 12) + (q << 4);
            const uint4 r0 = *(const uint4*)rg;
            const uint4 r1 = *(const uint4*)(rg + 8);
            float g[16];
            cvt8(r0, g); cvt8(r1, g + 8);
            float n0, n1, n2, n3;
            if (FWD) {
                const float b0 = buf[cur * 1024 + q];
                const float b1 = buf[cur * 1024 + q + 256];
                const float b2 = buf[cur * 1024 + q + 512];
                const float b3 = buf[cur * 1024 + q + 768];
                n0 = fmaf(STAYT, P0, fmaf(g[0],  b0, g[1]  * b1) + fmaf(g[2],  b2, g[3]  * b3));
                n1 = fmaf(STAYT, P1, fmaf(g[4],  b0, g[5]  * b1) + fmaf(g[6],  b2, g[7]  * b3));
                n2 = fmaf(STAYT, P2, fmaf(g[8],  b0, g[9]  * b1) + fmaf(g[10], b2, g[11] * b3));
                n3 = fmaf(STAYT, P3, fmaf(g[12], b0, g[13] * b1) + fmaf(g[14], b2, g[15] * b3));
            } else {
                const float4 b4 = *(const float4*)&buf[cur * 1024 + 4 * q];
                n0 = fmaf(STAYT, P0, fmaf(g[0], b4.x, g[4] * b4.y) + fmaf(g[8],  b4.z, g[12] * b4.w));
                n1 = fmaf(STAYT, P1, fmaf(g[1], b4.x, g[5] * b4.y) + fmaf(g[9],  b4.z, g[13] * b4.w));
                n2 = fmaf(STAYT, P2, fmaf(g[2], b4.x, g[6] * b4.y) + fmaf(g[10], b4.z, g[14] * b4.w));
                n3 = fmaf(STAYT, P3, fmaf(g[3], b4.x, g[7] * b4.y) + fmaf(g[11], b4.z, g[15] * b4.w));
            }
            if ((t & 7) == 1) {
                const float wm = fmaxf(fmaxf(wmax4[0], wmax4[1]), fmaxf(wmax4[2], wmax4[3]));
                const int e = (int)((__float_as_uint(wm) >> 23) & 0xff) - 127;
                const float c = __uint_as_float((unsigned)(127 - e) << 23);
                n0 *= c; n1 *= c; n2 *= c; n3 *= c;
                acc += (float)e;
            }
            P0 = n0; P1 = n1; P2 = n2; P3 = n3;
            if (FWD) {
                *(float4*)&buf[(cur ^ 1) * 1024 + 4 * q] = make_float4(P0, P1, P2, P3);
            } else {
                buf[(cur ^ 1) * 1024 + q]       = P0;
                buf[(cur ^ 1) * 1024 + q + 256] = P1;
                buf[(cur ^ 1) * 1024 + q + 512] = P2;
                buf[(cur ^ 1) * 1024 + q + 768] = P3;
            }
            if ((t & 7) == 0) {
                float m = fmaxf(fmaxf(P0, P1), fmaxf(P2, P3));
                #pragma unroll
                for (int msk = 1; msk < 64; msk <<= 1)
                    m = fmaxf(m, __shfl_xor(m, msk, 64));
                if (lane == 0) wmax4[w] = m;
            }
            asm volatile("s_waitcnt vmcnt(14)" ::: "memory");
            step_barrier();
            cur ^= 1;
        }
        if (FWD) {
            *(float4*)&FA[n * 1024 + 4 * q] = make_float4(P0, P1, P2, P3);
            if (q == 0) FAe[n] = acc;
        } else {
            FB[n * 1024 + q]       = P0;
            FB[n * 1024 + q + 256] = P1;
            FB[n * 1024 + q + 512] = P2;
            FB[n * 1024 + q + 768] = P3;
            if (q == 0) FBe[n] = acc;
        }
        #undef CRF_STAGE
    } else {
        // ---------------- CTC halves (log2 domain, G16 pre-gathered rows) ----------------
        unsigned short* rng = (unsigned short*)SH;           // [32][256]
        float* abuf = (float*)(SH + 16384);                  // [2][256]
        const bool FWD = (role == 2);
        const unsigned short* Gn = G16 + (size_t)n * T_STEPS * 256;
        const int li = ys_lens[n] - 5;                       // len - 1
        const bool val = FWD ? (q >= 1 && q < LMAX) : (q < LMAX - 1);
        const int myidx = FWD ? q : ((q + 1 < 256) ? q + 1 : 255);
        float a = FWD ? ((q == 0) ? 0.f : NEGF)
                      : ((q == li) ? 0.f : NEGF);
        abuf[q] = a;
        // prologue: wave 0 stages rows for steps 0..15 (1 instr per 2 steps)
        if (w == 0) {
            #pragma unroll
            for (int p = 0; p < 8; ++p) {
                const int s0 = 2 * p;
                const int rbase = FWD ? s0 : (510 - s0);
                gll16(Gn + (size_t)rbase * 256 + lane * 8, rng + ((s0 & 31) << 8));
            }
        }
        asm volatile("s_waitcnt vmcnt(0)" ::: "memory");
        step_barrier();
        const float STAY2 = (2.0f - 3.0f) * L2E;
        int cur = 0;
        for (int t = 0; t < 256; ++t) {
            if (((t & 1) == 0) && w == 0) {
                const int s0 = t + 16;
                const int rbase = FWD ? s0 : (510 - s0);
                gll16(Gn + (size_t)rbase * 256 + lane * 8, rng + ((s0 & 31) << 8));
            }
            const int slot = FWD ? (t & 31) : ((t & 31) ^ 1);
            const unsigned short gv = rng[(slot << 8) + myidx];
            const float g2 = val ? __builtin_amdgcn_logf(h2f(gv)) : NEGF;
            float nb;
            if (FWD) nb = (q > 0)   ? abuf[cur * 256 + q - 1] : NEGF;
            else     nb = (q < 255) ? abuf[cur * 256 + q + 1] : NEGF;
            const float st = a + STAY2;
            const float mv = nb + g2;
            const float mx = fmaxf(st, mv);
            const float mn = fminf(st, mv);
            a = mx + __builtin_amdgcn_logf(1.f + __builtin_amdgcn_exp2f(mn - mx));
            abuf[(cur ^ 1) * 256 + q] = a;
            if (((t & 1) == 0) && w == 0)
                asm volatile("s_waitcnt vmcnt(7)" ::: "memory");
            step_barrier();
            cur ^= 1;
        }
        if (FWD) CAL[n * 256 + q] = a;
        else     CBE[n * 256 + q] = a;
    }
}

// ---------------- combine + loss: out[n] = -((un - logZ)/len) ----------------
__global__ __launch_bounds__(256) void combine2_kernel(
    const float* __restrict__ FA, const float* __restrict__ FAe,
    const float* __restrict__ FB, const float* __restrict__ FBe,
    const float* __restrict__ CAL, const float* __restrict__ CBE,
    const int* __restrict__ ys_lens,
    float* __restrict__ out)
{
    __shared__ float red[256];
    __shared__ float lz;
    const int n = blockIdx.x;
    const int q = threadIdx.x;
    float s = 0.f;
    #pragma unroll
    for (int k = 0; k < 4; ++k)
        s += FA[n * 1024 + 4 * q + k] * FB[n * 1024 + 4 * q + k];
    red[q] = s; __syncthreads();
    for (int off = 128; off > 0; off >>= 1) {
        if (q < off) red[q] += red[q + off];
        __syncthreads();
    }
    if (q == 0) lz = FAe[n] + FBe[n] + __builtin_amdgcn_logf(red[0]);
    __syncthreads();
    const float x = CAL[n * 256 + q] + CBE[n * 256 + q];
    red[q] = x; __syncthreads();
    for (int off = 128; off > 0; off >>= 1) {
        if (q < off) red[q] = fmaxf(red[q], red[q + off]);
        __syncthreads();
    }
    const float m = red[0]; __syncthreads();
    red[q] = __builtin_amdgcn_exp2f(x - m); __syncthreads();
    for (int off = 128; off > 0; off >>= 1) {
        if (q < off) red[q] += red[q + off];
        __syncthreads();
    }
    if (q == 0) {
        const float un = m + __builtin_amdgcn_logf(red[0]);
        out[n] = -(LN2 * (un - lz) / (float)ys_lens[n]);
    }
}

// ---------------- fallback fused fwd on f32 interleaved scores (round-2, known-good) ----------------
__global__ __launch_bounds__(1024) void crf_fwd_kernel(
    const float* __restrict__ scores,
    const int* __restrict__ ys_pad,
    const int* __restrict__ ys_lens,
    float* __restrict__ ws)
{
    const int blk = blockIdx.x;
    const float STAY = 2.0f * L2E;
    if (blk < NB) {
        const int n = blk;
        const int s = threadIdx.x;
        __shared__ float buf[2][1024];
        __shared__ float red[1024];
        float alpha = 0.f;
        buf[0][s] = 0.f;
        const int j0 = s >> 2;
        const float* rowp = scores + (size_t)(n * T_STEPS) * CO + 5 * s + 1;
        float pm[4][4];
        #pragma unroll
        for (int u = 0; u < 4; ++u) {
            const float* r = rowp + (size_t)u * CO;
            pm[u][0] = r[0]; pm[u][1] = r[1]; pm[u][2] = r[2]; pm[u][3] = r[3];
        }
        __syncthreads();
        int cur = 0;
        for (int t = 0; t < T_STEPS; t += 4) {
            #pragma unroll
            for (int u = 0; u < 4; ++u) {
                const float m1 = pm[u][0], m2 = pm[u][1], m3 = pm[u][2], m4 = pm[u][3];
                int tp = t + u + 4; if (tp > T_STEPS - 1) tp = T_STEPS - 1;
                const float* r = rowp + (size_t)tp * CO;
                pm[u][0] = r[0]; pm[u][1] = r[1]; pm[u][2] = r[2]; pm[u][3] = r[3];
                const float b1 = buf[cur][j0];
                const float b2 = buf[cur][j0 + 256];
                const float b3 = buf[cur][j0 + 512];
                const float b4 = buf[cur][j0 + 768];
                const float a0 = alpha + STAY;
                const float a1 = fmaf(m1, L2E, b1);
                const float a2 = fmaf(m2, L2E, b2);
                const float a3 = fmaf(m3, L2E, b3);
                const float a4 = fmaf(m4, L2E, b4);
                const float mx = fmaxf(fmaxf(fmaxf(a0, a1), fmaxf(a2, a3)), a4);
                const float sum = __builtin_amdgcn_exp2f(a0 - mx) + __builtin_amdgcn_exp2f(a1 - mx)
                                + __builtin_amdgcn_exp2f(a2 - mx) + __builtin_amdgcn_exp2f(a3 - mx)
                                + __builtin_amdgcn_exp2f(a4 - mx);
                alpha = mx + __builtin_amdgcn_logf(sum);
                buf[cur ^ 1][s] = alpha;
                __syncthreads();
                cur ^= 1;
            }
        }
        red[s] = alpha;
        __syncthreads();
        for (int off = 512; off > 0; off >>= 1) {
            if (s < off) red[s] = fmaxf(red[s], red[s + off]);
            __syncthreads();
        }
        const float gmax = red[0];
        __syncthreads();
        red[s] = __builtin_amdgcn_exp2f(alpha - gmax);
        __syncthreads();
        for (int off = 512; off > 0; off >>= 1) {
            if (s < off) red[s] += red[s + off];
            __syncthreads();
        }
        if (s == 0) ws[n] = LN2 * (gmax + __builtin_amdgcn_logf(red[0]));
    } else {
        const int n = blk - NB;
        const int i = threadIdx.x;
        __shared__ float abuf[2][LMAX];
        __shared__ int tcl[256];
        if (i < 256) tcl[i] = max(ys_pad[n * 256 + i] - 1, 0);
        __syncthreads();
        int mch = -1;
        if (i >= 1 && i < LMAX) {
            const int code = tcl[i] * 256 + tcl[i + 1] * 64 + tcl[i + 2] * 16
                           + tcl[i + 3] * 4 + tcl[i + 4];
            mch = code * 5 + tcl[i - 1] + 1;
        }
        float alpha = (i == 0) ? 0.f : NEGF;
        if (i < LMAX) abuf[0][i] = alpha;
        const float* base = scores + (size_t)(n * T_STEPS) * CO;
        const size_t moff = (mch >= 0) ? (size_t)mch : 0;
        float pg[4];
        #pragma unroll
        for (int u = 0; u < 4; ++u) pg[u] = base[(size_t)u * CO + moff];
        __syncthreads();
        int cur = 0;
        for (int t = 0; t < T_STEPS; t += 4) {
            #pragma unroll
            for (int u = 0; u < 4; ++u) {
                const float g = pg[u];
                int tp = t + u + 4; if (tp > T_STEPS - 1) tp = T_STEPS - 1;
                pg[u] = base[(size_t)tp * CO + moff];
                if (i < LMAX) {
                    const float a_stay = alpha + STAY;
                    const float prev = (i > 0) ? abuf[cur][i - 1] : NEGF;
                    const float a_mv = (i > 0) ? fmaf(g, L2E, prev) : NEGF;
                    const float mx = fmaxf(a_stay, a_mv);
                    const float mn = fminf(a_stay, a_mv);
                    alpha = mx + __builtin_amdgcn_logf(1.f + __builtin_amdgcn_exp2f(mn - mx));
                    abuf[cur ^ 1][i] = alpha;
                }
                __syncthreads();
                cur ^= 1;
            }
        }
        if (i == ys_lens[n] - 5) ws[NB + n] = alpha * LN2;
    }
}

// ---------------- fallback loss ----------------
__global__ void crf_loss_kernel(const float* __restrict__ ws,
                                const int* __restrict__ ys_lens,
                                float* __restrict__ out)
{
    const int n = threadIdx.x;
    if (n < NB) {
        const float logz = ws[NB + n] - ws[n];
        out[n] = -(logz / (float)ys_lens[n]);
    }
}

extern "C" void kernel_launch(void* const* d_in, const int* in_sizes, int n_in,
                              void* d_out, int out_size, void* d_ws, size_t ws_size,
                              hipStream_t stream)
{
    const float* hs      = (const float*)d_in[0];
    const int*   ys_pad  = (const int*)d_in[2];
    const int*   ys_lens = (const int*)d_in[3];
    const float* W       = (const float*)d_in[4];
    const float* bias    = (const float*)d_in[5];
    float* out = (float*)d_out;
    float* ws  = (float*)d_ws;

    const size_t A_ELEMS = (size_t)8192 * 512;
    const size_t W_ELEMS = (size_t)4096 * 512;
    const size_t E_ELEMS = (size_t)8192 * 4096;
    const size_t G_ELEMS = (size_t)NB * T_STEPS * 256;
    const size_t X_FLOATS = (size_t)16 * 1024 * 2 + 32 + (size_t)16 * 256 * 2;
    const size_t NEED = 256 + (A_ELEMS + W_ELEMS + E_ELEMS + G_ELEMS) * 2 + X_FLOATS * 4;

    unsigned short* A16 = (unsigned short*)((char*)d_ws + 256);
    unsigned short* W16 = A16 + A_ELEMS;
    unsigned short* E16 = W16 + W_ELEMS;
    unsigned short* G16 = E16 + E_ELEMS;
    float* FA  = (float*)(G16 + G_ELEMS);
    float* FAe = FA + 16 * 1024;
    float* FB  = FAe + 16;
    float* FBe = FB + 16 * 1024;
    float* CAL = FBe + 16;
    float* CBE = CAL + 16 * 256;

    cvt_bf16_kernel<<<(int)(A_ELEMS / 4 / 256), 256, 0, stream>>>(hs, A16, (int)(A_ELEMS / 4));
    cvt_bf16_kernel<<<(int)(W_ELEMS / 4 / 256), 256, 0, stream>>>(W, W16, (int)(W_ELEMS / 4));
    dim3 grid(CG / 128, (NB * T_STEPS) / 128);

    if (ws_size >= NEED) {
        crf_gemm_bf16<true><<<grid, 256, 0, stream>>>(A16, W16, bias, out, E16);
        dim3 gg(T_STEPS / 32, NB);
        ctc_gather_kernel<<<gg, 256, 0, stream>>>(E16, ys_pad, G16);
        fb2_kernel<<<64, 256, 0, stream>>>(E16, G16, ys_lens, FA, FAe, FB, FBe, CAL, CBE);
        combine2_kernel<<<16, 256, 0, stream>>>(FA, FAe, FB, FBe, CAL, CBE, ys_lens, out);
    } else {
        crf_gemm_bf16<false><<<grid, 256, 0, stream>>>(A16, W16, bias, out, nullptr);
        crf_fwd_kernel<<<2 * NB, 1024, 0, stream>>>(out + 16, ys_pad, ys_lens, ws);
        crf_loss_kernel<<<1, 64, 0, stream>>>(ws, ys_lens, out);
    }
}

// Round 9
// 320.327 us; speedup vs baseline: 1.0595x; 1.0595x over previous
//
#include <hip/hip_runtime.h>
#include <hip/hip_bf16.h>
#include <hip/hip_fp16.h>
#include <math.h>

#define T_STEPS 512
#define NB      16
#define D_IN    512
#define CG      4096
#define CO      5120
#define LMAX    252
#define NEGF    (-1e30f)
#define SCORES_SZ 41943040LL   // NB * T_STEPS * CO
#define L2E 1.4426950408889634f
#define LN2 0.6931471805599453f
#define STAYT 0.36787944117144233f   // exp(2 - 3) tilted stay factor

typedef __attribute__((ext_vector_type(8))) short bf16x8;
typedef __attribute__((ext_vector_type(4))) float f32x4;

__device__ __forceinline__ float tanh5(float x) {
    x = fminf(fmaxf(x, -15.f), 15.f);
    float e = __expf(2.f * x);
    return 5.f * (e - 1.f) / (e + 1.f);
}
__device__ __forceinline__ unsigned short f2bf(float v) {
    __hip_bfloat16 h = __float2bfloat16(v);
    return *reinterpret_cast<unsigned short*>(&h);
}
__device__ __forceinline__ float h2f(unsigned short s) {
    union { unsigned short u; _Float16 h; } c; c.u = s;
    return (float)c.h;
}
__device__ __forceinline__ unsigned short f2h(float v) {
    union { unsigned short u; _Float16 h; } c; c.h = (_Float16)v;
    return c.u;
}
__device__ __forceinline__ void cvt8(uint4 u, float* g) {
    g[0] = h2f((unsigned short)(u.x & 0xffff)); g[1] = h2f((unsigned short)(u.x >> 16));
    g[2] = h2f((unsigned short)(u.y & 0xffff)); g[3] = h2f((unsigned short)(u.y >> 16));
    g[4] = h2f((unsigned short)(u.z & 0xffff)); g[5] = h2f((unsigned short)(u.z >> 16));
    g[6] = h2f((unsigned short)(u.w & 0xffff)); g[7] = h2f((unsigned short)(u.w >> 16));
}
// Clobber-free step barrier: lgkmcnt(0) drains LDS only; raw s_barrier does NOT
// drain vmcnt; sched_barrier(0) pins LDS ops on each side (rule #18). A "memory"
// clobber here would force the waitcnt pass to conservatively drain ALL in-flight
// global loads each step -- that was the ~1200 cyc/step invariant of rounds 2-8.
__device__ __forceinline__ void xbar() {
    __builtin_amdgcn_sched_barrier(0);
    asm volatile("s_waitcnt lgkmcnt(0)");
    __builtin_amdgcn_s_barrier();
    __builtin_amdgcn_sched_barrier(0);
}
__device__ __forceinline__ void gll16(const unsigned short* g, unsigned short* l) {
    __builtin_amdgcn_global_load_lds((const __attribute__((address_space(1))) void*)g,
                                     (__attribute__((address_space(3))) void*)l, 16, 0, 0);
}

// ---------------- fp32 -> bf16 conversion (RNE) ----------------
__global__ __launch_bounds__(256) void cvt_bf16_kernel(const float* __restrict__ src,
                                                       unsigned short* __restrict__ dst,
                                                       int n4) {
    int i = blockIdx.x * 256 + threadIdx.x;
    if (i < n4) {
        float4 v = *(reinterpret_cast<const float4*>(src) + i);
        ushort4 o;
        o.x = f2bf(v.x); o.y = f2bf(v.y); o.z = f2bf(v.z); o.w = f2bf(v.w);
        *(reinterpret_cast<ushort4*>(dst) + i) = o;
    }
}

// ---------------- bf16 MFMA GEMM + tanh*5 + blank interleave (+ tilted exp f16 copy) ----------------
template <bool WSE>
__global__ __launch_bounds__(256) void crf_gemm_bf16(
    const unsigned short* __restrict__ A16,
    const unsigned short* __restrict__ W16,
    const float* __restrict__ bias,
    float* __restrict__ out,
    unsigned short* __restrict__ e16)
{
    __shared__ unsigned short As[128 * 64];
    __shared__ unsigned short Bs[128 * 64];
    const int tid  = threadIdx.x;
    const int lane = tid & 63;
    const int wv   = __builtin_amdgcn_readfirstlane(tid >> 6);
    const int wr   = wv >> 1, wc = wv & 1;
    const int m0   = blockIdx.y * 128;
    const int n0   = blockIdx.x * 128;
    const int wbase = tid & 192;

    f32x4 acc[4][4];
    #pragma unroll
    for (int i = 0; i < 4; ++i)
        #pragma unroll
        for (int j = 0; j < 4; ++j) acc[i][j] = (f32x4){0.f, 0.f, 0.f, 0.f};

    const int l15 = lane & 15, lj = lane >> 4, l7 = lane & 7;

    for (int k0 = 0; k0 < D_IN; k0 += 64) {
        __syncthreads();
        #pragma unroll
        for (int i = 0; i < 4; ++i) {
            const int c   = i * 256 + tid;
            const int row = c >> 3;
            const int jg  = (c & 7) ^ (row & 7);
            const unsigned short* ga = A16 + (size_t)(m0 + row) * D_IN + k0 + jg * 8;
            const unsigned short* gb = W16 + (size_t)(n0 + row) * D_IN + k0 + jg * 8;
            gll16(ga, As + (size_t)(i * 256 + wbase) * 8);
            gll16(gb, Bs + (size_t)(i * 256 + wbase) * 8);
        }
        __syncthreads();
        #pragma unroll
        for (int ks = 0; ks < 2; ++ks) {
            bf16x8 af[4], bb[4];
            #pragma unroll
            for (int mi = 0; mi < 4; ++mi) {
                const int row = wr * 64 + mi * 16 + l15;
                const int jsw = (ks * 4 + lj) ^ l7;
                af[mi] = *reinterpret_cast<const bf16x8*>(&As[row * 64 + jsw * 8]);
            }
            #pragma unroll
            for (int ni = 0; ni < 4; ++ni) {
                const int row = wc * 64 + ni * 16 + l15;
                const int jsw = (ks * 4 + lj) ^ l7;
                bb[ni] = *reinterpret_cast<const bf16x8*>(&Bs[row * 64 + jsw * 8]);
            }
            #pragma unroll
            for (int mi = 0; mi < 4; ++mi)
                #pragma unroll
                for (int ni = 0; ni < 4; ++ni)
                    acc[mi][ni] = __builtin_amdgcn_mfma_f32_16x16x32_bf16(
                        af[mi], bb[ni], acc[mi][ni], 0, 0, 0);
        }
    }

    float bv[4];
    #pragma unroll
    for (int ni = 0; ni < 4; ++ni) bv[ni] = bias[n0 + wc * 64 + ni * 16 + l15];

    #pragma unroll
    for (int mi = 0; mi < 4; ++mi) {
        #pragma unroll
        for (int r = 0; r < 4; ++r) {
            const int m = m0 + wr * 64 + mi * 16 + lj * 4 + r;
            float* r1 = out + 16 + (size_t)m * CO;
            #pragma unroll
            for (int ni = 0; ni < 4; ++ni) {
                const int n = n0 + wc * 64 + ni * 16 + l15;
                const float v = tanh5(acc[mi][ni][r] + bv[ni]);
                const int ch = (n >> 2) * 5 + (n & 3) + 1;
                r1[ch] = v;
                r1[ch + SCORES_SZ] = v;
                if ((l15 & 3) == 0) {
                    r1[ch - 1] = 2.0f;
                    r1[ch - 1 + SCORES_SZ] = 2.0f;
                }
                if (WSE) e16[(size_t)m * CG + n] = f2h(__expf(v - 3.0f));
            }
        }
    }
}

// ---------------- bidirectional fwd/bwd (counted vmcnt ring + reg pipeline, clobber-free) ----------------
// 64 blocks x 256 threads. role: 0=CRF fwd, 1=CRF bwd, 2=CTC fwd, 3=CTC bwd.
// CRF (prob domain): gll16 ring [16 slots x 8KB], staged 8 steps ahead; thread q reads the
// region its OWN wave staged, so visibility needs only vmcnt(14) (2 loads/wave/step).
// CTC (log2 domain): per-lane 2B gather, 16-deep register pipeline; compiler emits counted
// vmcnt before each use (no clobbered asm to poison it).
__global__ __launch_bounds__(256) void fb2_kernel(
    const unsigned short* __restrict__ e16,
    const int* __restrict__ ys_pad,
    const int* __restrict__ ys_lens,
    float* __restrict__ FA, float* __restrict__ FAe,
    float* __restrict__ FB, float* __restrict__ FBe,
    float* __restrict__ CAL, float* __restrict__ CBE)
{
    __shared__ unsigned char SH[139284];
    const int role = blockIdx.x >> 4;
    const int n = blockIdx.x & 15;
    const int q = threadIdx.x;
    const int w = q >> 6, lane = q & 63;
    if (role < 2) {
        // ---------------- CRF halves (prob domain) ----------------
        unsigned short* ring = (unsigned short*)SH;          // [16][4096]
        float* buf   = (float*)(SH + 131072);                // [2][1024]
        float* wmax4 = (float*)(SH + 131072 + 8192);
        const bool FWD = (role == 0);
        const unsigned short* eb = e16 + (size_t)(n * T_STEPS) * CG;
        float P0 = 1.f, P1 = 1.f, P2 = 1.f, P3 = 1.f, acc = 0.f;
        *(float4*)&buf[4 * q] = make_float4(1.f, 1.f, 1.f, 1.f);

        #define CRF_STAGE(s) {                                                        \
            const int rr = ((s) < 256) ? (s) : 255;                                   \
            const int erow = FWD ? rr : (511 - rr);                                   \
            const unsigned short* ga = eb + (size_t)erow * CG + (w << 10) + lane * 8; \
            unsigned short* la = ring + (((s) & 15) << 12) + (w << 10) + lane * 8;    \
            gll16(ga, la);                                                            \
            gll16(ga + 512, la + 512); }

        #pragma unroll
        for (int s = 0; s < 8; ++s) CRF_STAGE(s);
        xbar();
        int cur = 0;
        for (int t = 0; t < 256; ++t) {
            CRF_STAGE(t + 8);
            __builtin_amdgcn_sched_barrier(0);
            asm volatile("s_waitcnt vmcnt(14)");   // slot t's pair (issued at t-8) complete
            __builtin_amdgcn_sched_barrier(0);
            const unsigned short* rg = ring + ((t & 15) << 12) + (q << 4);
            const uint4 r0 = *(const uint4*)rg;
            const uint4 r1 = *(const uint4*)(rg + 8);
            float g[16];
            cvt8(r0, g); cvt8(r1, g + 8);
            float n0, n1, n2, n3;
            if (FWD) {
                const float b0 = buf[cur * 1024 + q];
                const float b1 = buf[cur * 1024 + q + 256];
                const float b2 = buf[cur * 1024 + q + 512];
                const float b3 = buf[cur * 1024 + q + 768];
                n0 = fmaf(STAYT, P0, fmaf(g[0],  b0, g[1]  * b1) + fmaf(g[2],  b2, g[3]  * b3));
                n1 = fmaf(STAYT, P1, fmaf(g[4],  b0, g[5]  * b1) + fmaf(g[6],  b2, g[7]  * b3));
                n2 = fmaf(STAYT, P2, fmaf(g[8],  b0, g[9]  * b1) + fmaf(g[10], b2, g[11] * b3));
                n3 = fmaf(STAYT, P3, fmaf(g[12], b0, g[13] * b1) + fmaf(g[14], b2, g[15] * b3));
            } else {
                const float4 b4 = *(const float4*)&buf[cur * 1024 + 4 * q];
                n0 = fmaf(STAYT, P0, fmaf(g[0], b4.x, g[4] * b4.y) + fmaf(g[8],  b4.z, g[12] * b4.w));
                n1 = fmaf(STAYT, P1, fmaf(g[1], b4.x, g[5] * b4.y) + fmaf(g[9],  b4.z, g[13] * b4.w));
                n2 = fmaf(STAYT, P2, fmaf(g[2], b4.x, g[6] * b4.y) + fmaf(g[10], b4.z, g[14] * b4.w));
                n3 = fmaf(STAYT, P3, fmaf(g[3], b4.x, g[7] * b4.y) + fmaf(g[11], b4.z, g[15] * b4.w));
            }
            if ((t & 7) == 1) {
                const float wm = fmaxf(fmaxf(wmax4[0], wmax4[1]), fmaxf(wmax4[2], wmax4[3]));
                const int e = (int)((__float_as_uint(wm) >> 23) & 0xff) - 127;
                const float c = __uint_as_float((unsigned)(127 - e) << 23);
                n0 *= c; n1 *= c; n2 *= c; n3 *= c;
                acc += (float)e;
            }
            P0 = n0; P1 = n1; P2 = n2; P3 = n3;
            if (FWD) {
                *(float4*)&buf[(cur ^ 1) * 1024 + 4 * q] = make_float4(P0, P1, P2, P3);
            } else {
                buf[(cur ^ 1) * 1024 + q]       = P0;
                buf[(cur ^ 1) * 1024 + q + 256] = P1;
                buf[(cur ^ 1) * 1024 + q + 512] = P2;
                buf[(cur ^ 1) * 1024 + q + 768] = P3;
            }
            if ((t & 7) == 0) {
                float m = fmaxf(fmaxf(P0, P1), fmaxf(P2, P3));
                #pragma unroll
                for (int msk = 1; msk < 64; msk <<= 1)
                    m = fmaxf(m, __shfl_xor(m, msk, 64));
                if (lane == 0) wmax4[w] = m;
            }
            xbar();
            cur ^= 1;
        }
        if (FWD) {
            *(float4*)&FA[n * 1024 + 4 * q] = make_float4(P0, P1, P2, P3);
            if (q == 0) FAe[n] = acc;
        } else {
            FB[n * 1024 + q]       = P0;
            FB[n * 1024 + q + 256] = P1;
            FB[n * 1024 + q + 512] = P2;
            FB[n * 1024 + q + 768] = P3;
            if (q == 0) FBe[n] = acc;
        }
        #undef CRF_STAGE
    } else {
        // ---------------- CTC halves (log2 domain, per-lane reg pipeline) ----------------
        float* abuf = (float*)SH;                            // [2][256]
        int* tcl = (int*)(SH + 2048);
        const bool FWD = (role == 2);
        tcl[q] = max(ys_pad[n * 256 + q] - 1, 0);
        xbar();
        int mch = 0; bool val;
        if (FWD) {
            val = (q >= 1 && q < LMAX);
            if (val) {
                const int code = tcl[q] * 256 + tcl[q + 1] * 64 + tcl[q + 2] * 16
                               + tcl[q + 3] * 4 + tcl[q + 4];
                mch = code * 4 + tcl[q - 1];
            }
        } else {
            val = (q < LMAX - 1);            // move into position q+1
            if (val) {
                const int code = tcl[q + 1] * 256 + tcl[q + 2] * 64 + tcl[q + 3] * 16
                               + tcl[q + 4] * 4 + tcl[q + 5];
                mch = code * 4 + tcl[q];
            }
        }
        const int li = ys_lens[n] - 5;       // len - 1
        float a = FWD ? ((q == 0) ? 0.f : NEGF)
                      : ((q == li) ? 0.f : NEGF);
        abuf[q] = a;
        const unsigned short* eb = e16 + (size_t)(n * T_STEPS) * CG + mch;
        unsigned short pv[16];
        #pragma unroll
        for (int s = 0; s < 16; ++s) {
            const int row = FWD ? s : (511 - s);
            pv[s] = eb[(size_t)row * CG];
        }
        xbar();
        const float STAY2 = (2.0f - 3.0f) * L2E;
        int cur = 0;
        for (int t = 0; t < 256; t += 16) {
            #pragma unroll
            for (int u = 0; u < 16; ++u) {
                const float g2 = val ? __builtin_amdgcn_logf(h2f(pv[u])) : NEGF;
                int tn = t + u + 16; if (tn > 255) tn = 255;
                const int row = FWD ? tn : (511 - tn);
                pv[u] = eb[(size_t)row * CG];
                float nb;
                if (FWD) nb = (q > 0)   ? abuf[cur * 256 + q - 1] : NEGF;
                else     nb = (q < 255) ? abuf[cur * 256 + q + 1] : NEGF;
                const float st = a + STAY2;
                const float mv = nb + g2;
                const float mx = fmaxf(st, mv);
                const float mn = fminf(st, mv);
                a = mx + __builtin_amdgcn_logf(1.f + __builtin_amdgcn_exp2f(mn - mx));
                abuf[(cur ^ 1) * 256 + q] = a;
                xbar();
                cur ^= 1;
            }
        }
        if (FWD) CAL[n * 256 + q] = a;
        else     CBE[n * 256 + q] = a;
    }
}

// ---------------- combine + loss: out[n] = -((un - logZ)/len) ----------------
__global__ __launch_bounds__(256) void combine2_kernel(
    const float* __restrict__ FA, const float* __restrict__ FAe,
    const float* __restrict__ FB, const float* __restrict__ FBe,
    const float* __restrict__ CAL, const float* __restrict__ CBE,
    const int* __restrict__ ys_lens,
    float* __restrict__ out)
{
    __shared__ float red[256];
    __shared__ float lz;
    const int n = blockIdx.x;
    const int q = threadIdx.x;
    float s = 0.f;
    #pragma unroll
    for (int k = 0; k < 4; ++k)
        s += FA[n * 1024 + 4 * q + k] * FB[n * 1024 + 4 * q + k];
    red[q] = s; __syncthreads();
    for (int off = 128; off > 0; off >>= 1) {
        if (q < off) red[q] += red[q + off];
        __syncthreads();
    }
    if (q == 0) lz = FAe[n] + FBe[n] + __builtin_amdgcn_logf(red[0]);
    __syncthreads();
    const float x = CAL[n * 256 + q] + CBE[n * 256 + q];
    red[q] = x; __syncthreads();
    for (int off = 128; off > 0; off >>= 1) {
        if (q < off) red[q] = fmaxf(red[q], red[q + off]);
        __syncthreads();
    }
    const float m = red[0]; __syncthreads();
    red[q] = __builtin_amdgcn_exp2f(x - m); __syncthreads();
    for (int off = 128; off > 0; off >>= 1) {
        if (q < off) red[q] += red[q + off];
        __syncthreads();
    }
    if (q == 0) {
        const float un = m + __builtin_amdgcn_logf(red[0]);
        out[n] = -(LN2 * (un - lz) / (float)ys_lens[n]);
    }
}

// ---------------- fallback fused fwd on f32 interleaved scores (round-2, known-good) ----------------
__global__ __launch_bounds__(1024) void crf_fwd_kernel(
    const float* __restrict__ scores,
    const int* __restrict__ ys_pad,
    const int* __restrict__ ys_lens,
    float* __restrict__ ws)
{
    const int blk = blockIdx.x;
    const float STAY = 2.0f * L2E;
    if (blk < NB) {
        const int n = blk;
        const int s = threadIdx.x;
        __shared__ float buf[2][1024];
        __shared__ float red[1024];
        float alpha = 0.f;
        buf[0][s] = 0.f;
        const int j0 = s >> 2;
        const float* rowp = scores + (size_t)(n * T_STEPS) * CO + 5 * s + 1;
        float pm[4][4];
        #pragma unroll
        for (int u = 0; u < 4; ++u) {
            const float* r = rowp + (size_t)u * CO;
            pm[u][0] = r[0]; pm[u][1] = r[1]; pm[u][2] = r[2]; pm[u][3] = r[3];
        }
        __syncthreads();
        int cur = 0;
        for (int t = 0; t < T_STEPS; t += 4) {
            #pragma unroll
            for (int u = 0; u < 4; ++u) {
                const float m1 = pm[u][0], m2 = pm[u][1], m3 = pm[u][2], m4 = pm[u][3];
                int tp = t + u + 4; if (tp > T_STEPS - 1) tp = T_STEPS - 1;
                const float* r = rowp + (size_t)tp * CO;
                pm[u][0] = r[0]; pm[u][1] = r[1]; pm[u][2] = r[2]; pm[u][3] = r[3];
                const float b1 = buf[cur][j0];
                const float b2 = buf[cur][j0 + 256];
                const float b3 = buf[cur][j0 + 512];
                const float b4 = buf[cur][j0 + 768];
                const float a0 = alpha + STAY;
                const float a1 = fmaf(m1, L2E, b1);
                const float a2 = fmaf(m2, L2E, b2);
                const float a3 = fmaf(m3, L2E, b3);
                const float a4 = fmaf(m4, L2E, b4);
                const float mx = fmaxf(fmaxf(fmaxf(a0, a1), fmaxf(a2, a3)), a4);
                const float sum = __builtin_amdgcn_exp2f(a0 - mx) + __builtin_amdgcn_exp2f(a1 - mx)
                                + __builtin_amdgcn_exp2f(a2 - mx) + __builtin_amdgcn_exp2f(a3 - mx)
                                + __builtin_amdgcn_exp2f(a4 - mx);
                alpha = mx + __builtin_amdgcn_logf(sum);
                buf[cur ^ 1][s] = alpha;
                __syncthreads();
                cur ^= 1;
            }
        }
        red[s] = alpha;
        __syncthreads();
        for (int off = 512; off > 0; off >>= 1) {
            if (s < off) red[s] = fmaxf(red[s], red[s + off]);
            __syncthreads();
        }
        const float gmax = red[0];
        __syncthreads();
        red[s] = __builtin_amdgcn_exp2f(alpha - gmax);
        __syncthreads();
        for (int off = 512; off > 0; off >>= 1) {
            if (s < off) red[s] += red[s + off];
            __syncthreads();
        }
        if (s == 0) ws[n] = LN2 * (gmax + __builtin_amdgcn_logf(red[0]));
    } else {
        const int n = blk - NB;
        const int i = threadIdx.x;
        __shared__ float abuf[2][LMAX];
        __shared__ int tcl[256];
        if (i < 256) tcl[i] = max(ys_pad[n * 256 + i] - 1, 0);
        __syncthreads();
        int mch = -1;
        if (i >= 1 && i < LMAX) {
            const int code = tcl[i] * 256 + tcl[i + 1] * 64 + tcl[i + 2] * 16
                           + tcl[i + 3] * 4 + tcl[i + 4];
            mch = code * 5 + tcl[i - 1] + 1;
        }
        float alpha = (i == 0) ? 0.f : NEGF;
        if (i < LMAX) abuf[0][i] = alpha;
        const float* base = scores + (size_t)(n * T_STEPS) * CO;
        const size_t moff = (mch >= 0) ? (size_t)mch : 0;
        float pg[4];
        #pragma unroll
        for (int u = 0; u < 4; ++u) pg[u] = base[(size_t)u * CO + moff];
        __syncthreads();
        int cur = 0;
        for (int t = 0; t < T_STEPS; t += 4) {
            #pragma unroll
            for (int u = 0; u < 4; ++u) {
                const float g = pg[u];
                int tp = t + u + 4; if (tp > T_STEPS - 1) tp = T_STEPS - 1;
                pg[u] = base[(size_t)tp * CO + moff];
                if (i < LMAX) {
                    const float a_stay = alpha + STAY;
                    const float prev = (i > 0) ? abuf[cur][i - 1] : NEGF;
                    const float a_mv = (i > 0) ? fmaf(g, L2E, prev) : NEGF;
                    const float mx = fmaxf(a_stay, a_mv);
                    const float mn = fminf(a_stay, a_mv);
                    alpha = mx + __builtin_amdgcn_logf(1.f + __builtin_amdgcn_exp2f(mn - mx));
                    abuf[cur ^ 1][i] = alpha;
                }
                __syncthreads();
                cur ^= 1;
            }
        }
        if (i == ys_lens[n] - 5) ws[NB + n] = alpha * LN2;
    }
}

// ---------------- fallback loss ----------------
__global__ void crf_loss_kernel(const float* __restrict__ ws,
                                const int* __restrict__ ys_lens,
                                float* __restrict__ out)
{
    const int n = threadIdx.x;
    if (n < NB) {
        const float logz = ws[NB + n] - ws[n];
        out[n] = -(logz / (float)ys_lens[n]);
    }
}

extern "C" void kernel_launch(void* const* d_in, const int* in_sizes, int n_in,
                              void* d_out, int out_size, void* d_ws, size_t ws_size,
                              hipStream_t stream)
{
    const float* hs      = (const float*)d_in[0];
    const int*   ys_pad  = (const int*)d_in[2];
    const int*   ys_lens = (const int*)d_in[3];
    const float* W       = (const float*)d_in[4];
    const float* bias    = (const float*)d_in[5];
    float* out = (float*)d_out;
    float* ws  = (float*)d_ws;

    const size_t A_ELEMS = (size_t)8192 * 512;
    const size_t W_ELEMS = (size_t)4096 * 512;
    const size_t E_ELEMS = (size_t)8192 * 4096;
    const size_t X_FLOATS = (size_t)16 * 1024 * 2 + 32 + (size_t)16 * 256 * 2;
    const size_t NEED = 256 + (A_ELEMS + W_ELEMS + E_ELEMS) * 2 + X_FLOATS * 4;

    unsigned short* A16 = (unsigned short*)((char*)d_ws + 256);
    unsigned short* W16 = A16 + A_ELEMS;
    unsigned short* E16 = W16 + W_ELEMS;
    float* FA  = (float*)(E16 + E_ELEMS);
    float* FAe = FA + 16 * 1024;
    float* FB  = FAe + 16;
    float* FBe = FB + 16 * 1024;
    float* CAL = FBe + 16;
    float* CBE = CAL + 16 * 256;

    cvt_bf16_kernel<<<(int)(A_ELEMS / 4 / 256), 256, 0, stream>>>(hs, A16, (int)(A_ELEMS / 4));
    cvt_bf16_kernel<<<(int)(W_ELEMS / 4 / 256), 256, 0, stream>>>(W, W16, (int)(W_ELEMS / 4));
    dim3 grid(CG / 128, (NB * T_STEPS) / 128);

    if (ws_size >= NEED) {
        crf_gemm_bf16<true><<<grid, 256, 0, stream>>>(A16, W16, bias, out, E16);
        fb2_kernel<<<64, 256, 0, stream>>>(E16, ys_pad, ys_lens, FA, FAe, FB, FBe, CAL, CBE);
        combine2_kernel<<<16, 256, 0, stream>>>(FA, FAe, FB, FBe, CAL, CBE, ys_lens, out);
    } else {
        crf_gemm_bf16<false><<<grid, 256, 0, stream>>>(A16, W16, bias, out, nullptr);
        crf_fwd_kernel<<<2 * NB, 1024, 0, stream>>>(out + 16, ys_pad, ys_lens, ws);
        crf_loss_kernel<<<1, 64, 0, stream>>>(ws, ys_lens, out);
    }
}

// Round 10
// 213.955 us; speedup vs baseline: 1.5862x; 1.4972x over previous
//
#include <hip/hip_runtime.h>
#include <hip/hip_bf16.h>
#include <hip/hip_fp16.h>
#include <math.h>

#define T_STEPS 512
#define NB      16
#define D_IN    512
#define CG      4096
#define CO      5120
#define LMAX    252
#define NEGF    (-1e30f)
#define SCORES_SZ 41943040LL   // NB * T_STEPS * CO
#define L2E 1.4426950408889634f
#define LN2 0.6931471805599453f
#define STAYT 0.36787944117144233f   // exp(2 - 3) tilted stay factor

typedef __attribute__((ext_vector_type(8))) short bf16x8;
typedef __attribute__((ext_vector_type(4))) float f32x4;

__device__ __forceinline__ float tanh5(float x) {
    x = fminf(fmaxf(x, -15.f), 15.f);
    float e = __expf(2.f * x);
    return 5.f * (e - 1.f) / (e + 1.f);
}
__device__ __forceinline__ unsigned short f2bf(float v) {
    __hip_bfloat16 h = __float2bfloat16(v);
    return *reinterpret_cast<unsigned short*>(&h);
}
__device__ __forceinline__ float h2f(unsigned short s) {
    union { unsigned short u; _Float16 h; } c; c.u = s;
    return (float)c.h;
}
__device__ __forceinline__ unsigned short f2h(float v) {
    union { unsigned short u; _Float16 h; } c; c.h = (_Float16)v;
    return c.u;
}
__device__ __forceinline__ void cvt8(uint4 u, float* g) {
    g[0] = h2f((unsigned short)(u.x & 0xffff)); g[1] = h2f((unsigned short)(u.x >> 16));
    g[2] = h2f((unsigned short)(u.y & 0xffff)); g[3] = h2f((unsigned short)(u.y >> 16));
    g[4] = h2f((unsigned short)(u.z & 0xffff)); g[5] = h2f((unsigned short)(u.z >> 16));
    g[6] = h2f((unsigned short)(u.w & 0xffff)); g[7] = h2f((unsigned short)(u.w >> 16));
}
// Clobber-free LDS-only step barrier (m201 pattern). NO "memory" clobber anywhere:
// a clobber forces the waitcnt pass to conservatively drain ALL in-flight global
// loads each step (the ~1200 cyc/step invariant of rounds 2-9). lgkmcnt(0) orders
// the LDS alpha exchange; raw s_barrier does NOT drain vmcnt; sched_barrier(0)
// pins machine-level scheduling on both sides (guide rule #18).
__device__ __forceinline__ void xbar() {
    __builtin_amdgcn_sched_barrier(0);
    asm volatile("s_waitcnt lgkmcnt(0)");
    __builtin_amdgcn_s_barrier();
    __builtin_amdgcn_sched_barrier(0);
}
__device__ __forceinline__ void gll16(const unsigned short* g, unsigned short* l) {
    __builtin_amdgcn_global_load_lds((const __attribute__((address_space(1))) void*)g,
                                     (__attribute__((address_space(3))) void*)l, 16, 0, 0);
}

// ---------------- fp32 -> bf16 conversion (RNE) ----------------
__global__ __launch_bounds__(256) void cvt_bf16_kernel(const float* __restrict__ src,
                                                       unsigned short* __restrict__ dst,
                                                       int n4) {
    int i = blockIdx.x * 256 + threadIdx.x;
    if (i < n4) {
        float4 v = *(reinterpret_cast<const float4*>(src) + i);
        ushort4 o;
        o.x = f2bf(v.x); o.y = f2bf(v.y); o.z = f2bf(v.z); o.w = f2bf(v.w);
        *(reinterpret_cast<ushort4*>(dst) + i) = o;
    }
}

// ---------------- bf16 MFMA GEMM + tanh*5 + blank interleave (+ tilted exp f16 copy) ----------------
template <bool WSE>
__global__ __launch_bounds__(256) void crf_gemm_bf16(
    const unsigned short* __restrict__ A16,
    const unsigned short* __restrict__ W16,
    const float* __restrict__ bias,
    float* __restrict__ out,
    unsigned short* __restrict__ e16)
{
    __shared__ unsigned short As[128 * 64];
    __shared__ unsigned short Bs[128 * 64];
    const int tid  = threadIdx.x;
    const int lane = tid & 63;
    const int wv   = __builtin_amdgcn_readfirstlane(tid >> 6);
    const int wr   = wv >> 1, wc = wv & 1;
    const int m0   = blockIdx.y * 128;
    const int n0   = blockIdx.x * 128;
    const int wbase = tid & 192;

    f32x4 acc[4][4];
    #pragma unroll
    for (int i = 0; i < 4; ++i)
        #pragma unroll
        for (int j = 0; j < 4; ++j) acc[i][j] = (f32x4){0.f, 0.f, 0.f, 0.f};

    const int l15 = lane & 15, lj = lane >> 4, l7 = lane & 7;

    for (int k0 = 0; k0 < D_IN; k0 += 64) {
        __syncthreads();
        #pragma unroll
        for (int i = 0; i < 4; ++i) {
            const int c   = i * 256 + tid;
            const int row = c >> 3;
            const int jg  = (c & 7) ^ (row & 7);
            const unsigned short* ga = A16 + (size_t)(m0 + row) * D_IN + k0 + jg * 8;
            const unsigned short* gb = W16 + (size_t)(n0 + row) * D_IN + k0 + jg * 8;
            gll16(ga, As + (size_t)(i * 256 + wbase) * 8);
            gll16(gb, Bs + (size_t)(i * 256 + wbase) * 8);
        }
        __syncthreads();
        #pragma unroll
        for (int ks = 0; ks < 2; ++ks) {
            bf16x8 af[4], bb[4];
            #pragma unroll
            for (int mi = 0; mi < 4; ++mi) {
                const int row = wr * 64 + mi * 16 + l15;
                const int jsw = (ks * 4 + lj) ^ l7;
                af[mi] = *reinterpret_cast<const bf16x8*>(&As[row * 64 + jsw * 8]);
            }
            #pragma unroll
            for (int ni = 0; ni < 4; ++ni) {
                const int row = wc * 64 + ni * 16 + l15;
                const int jsw = (ks * 4 + lj) ^ l7;
                bb[ni] = *reinterpret_cast<const bf16x8*>(&Bs[row * 64 + jsw * 8]);
            }
            #pragma unroll
            for (int mi = 0; mi < 4; ++mi)
                #pragma unroll
                for (int ni = 0; ni < 4; ++ni)
                    acc[mi][ni] = __builtin_amdgcn_mfma_f32_16x16x32_bf16(
                        af[mi], bb[ni], acc[mi][ni], 0, 0, 0);
        }
    }

    float bv[4];
    #pragma unroll
    for (int ni = 0; ni < 4; ++ni) bv[ni] = bias[n0 + wc * 64 + ni * 16 + l15];

    #pragma unroll
    for (int mi = 0; mi < 4; ++mi) {
        #pragma unroll
        for (int r = 0; r < 4; ++r) {
            const int m = m0 + wr * 64 + mi * 16 + lj * 4 + r;
            float* r1 = out + 16 + (size_t)m * CO;
            #pragma unroll
            for (int ni = 0; ni < 4; ++ni) {
                const int n = n0 + wc * 64 + ni * 16 + l15;
                const float v = tanh5(acc[mi][ni][r] + bv[ni]);
                const int ch = (n >> 2) * 5 + (n & 3) + 1;
                r1[ch] = v;
                r1[ch + SCORES_SZ] = v;
                if ((l15 & 3) == 0) {
                    r1[ch - 1] = 2.0f;
                    r1[ch - 1 + SCORES_SZ] = 2.0f;
                }
                if (WSE) e16[(size_t)m * CG + n] = f2h(__expf(v - 3.0f));
            }
        }
    }
}

// ---------------- bidirectional fwd/bwd: register prefetch + clobber-free barrier ----------------
// 64 blocks x 256 threads. role: 0=CRF fwd, 1=CRF bwd, 2=CTC fwd, 3=CTC bwd.
// CRF (prob domain): per-thread uint4 register prefetch, depth 8 (16 loads in flight,
// compiler emits counted vmcnt before each use). f32 LDS alpha exchange; pow2 renorm
// (reduce at t%8==0 off-chain, apply 2-stale at t%8==1).
// CTC (log2 domain): per-lane 2B gather, depth-16 register pipeline.
__global__ __launch_bounds__(256) void fb2_kernel(
    const unsigned short* __restrict__ e16,
    const int* __restrict__ ys_pad,
    const int* __restrict__ ys_lens,
    float* __restrict__ FA, float* __restrict__ FAe,
    float* __restrict__ FB, float* __restrict__ FBe,
    float* __restrict__ CAL, float* __restrict__ CBE)
{
    __shared__ float buf[2][1024];
    __shared__ float wmax4[4];
    __shared__ int tcl[256];
    const int role = blockIdx.x >> 4;
    const int n = blockIdx.x & 15;
    const int q = threadIdx.x;
    const int w = q >> 6, lane = q & 63;
    if (role < 2) {
        // ---------------- CRF halves (prob domain) ----------------
        const bool FWD = (role == 0);
        const unsigned short* eb = e16 + (size_t)(n * T_STEPS) * CG + 16 * q;
        float P0 = 1.f, P1 = 1.f, P2 = 1.f, P3 = 1.f, acc = 0.f;
        *(float4*)&buf[0][4 * q] = make_float4(1.f, 1.f, 1.f, 1.f);
        uint4 pf[8][2];
        #pragma unroll
        for (int u = 0; u < 8; ++u) {
            const int row = FWD ? u : (511 - u);
            pf[u][0] = *(const uint4*)(eb + (size_t)row * CG);
            pf[u][1] = *(const uint4*)(eb + (size_t)row * CG + 8);
        }
        xbar();
        int cur = 0;
        for (int t = 0; t < 256; t += 8) {
            #pragma unroll
            for (int u = 0; u < 8; ++u) {
                float g[16];
                cvt8(pf[u][0], g);
                cvt8(pf[u][1], g + 8);
                int tn = t + u + 8; if (tn > 255) tn = 255;
                const int row = FWD ? tn : (511 - tn);
                pf[u][0] = *(const uint4*)(eb + (size_t)row * CG);
                pf[u][1] = *(const uint4*)(eb + (size_t)row * CG + 8);
                float n0, n1, n2, n3;
                if (FWD) {
                    // state s=4q+d gets B[q+256m] with weight g[4d+m]
                    const float b0 = buf[cur][q];
                    const float b1 = buf[cur][q + 256];
                    const float b2 = buf[cur][q + 512];
                    const float b3 = buf[cur][q + 768];
                    n0 = fmaf(STAYT, P0, fmaf(g[0],  b0, g[1]  * b1) + fmaf(g[2],  b2, g[3]  * b3));
                    n1 = fmaf(STAYT, P1, fmaf(g[4],  b0, g[5]  * b1) + fmaf(g[6],  b2, g[7]  * b3));
                    n2 = fmaf(STAYT, P2, fmaf(g[8],  b0, g[9]  * b1) + fmaf(g[10], b2, g[11] * b3));
                    n3 = fmaf(STAYT, P3, fmaf(g[12], b0, g[13] * b1) + fmaf(g[14], b2, g[15] * b3));
                } else {
                    // state p=q+256m gets B[4q+d] with weight g[4d+m]
                    const float4 b4 = *(const float4*)&buf[cur][4 * q];
                    n0 = fmaf(STAYT, P0, fmaf(g[0], b4.x, g[4] * b4.y) + fmaf(g[8],  b4.z, g[12] * b4.w));
                    n1 = fmaf(STAYT, P1, fmaf(g[1], b4.x, g[5] * b4.y) + fmaf(g[9],  b4.z, g[13] * b4.w));
                    n2 = fmaf(STAYT, P2, fmaf(g[2], b4.x, g[6] * b4.y) + fmaf(g[10], b4.z, g[14] * b4.w));
                    n3 = fmaf(STAYT, P3, fmaf(g[3], b4.x, g[7] * b4.y) + fmaf(g[11], b4.z, g[15] * b4.w));
                }
                if (((t + u) & 7) == 1) {
                    const float wm = fmaxf(fmaxf(wmax4[0], wmax4[1]), fmaxf(wmax4[2], wmax4[3]));
                    const int e = (int)((__float_as_uint(wm) >> 23) & 0xff) - 127;
                    const float c = __uint_as_float((unsigned)(127 - e) << 23);
                    n0 *= c; n1 *= c; n2 *= c; n3 *= c;
                    acc += (float)e;
                }
                P0 = n0; P1 = n1; P2 = n2; P3 = n3;
                if (FWD) {
                    *(float4*)&buf[cur ^ 1][4 * q] = make_float4(P0, P1, P2, P3);
                } else {
                    buf[cur ^ 1][q]       = P0;
                    buf[cur ^ 1][q + 256] = P1;
                    buf[cur ^ 1][q + 512] = P2;
                    buf[cur ^ 1][q + 768] = P3;
                }
                if (((t + u) & 7) == 0) {
                    float m = fmaxf(fmaxf(P0, P1), fmaxf(P2, P3));
                    #pragma unroll
                    for (int msk = 1; msk < 64; msk <<= 1)
                        m = fmaxf(m, __shfl_xor(m, msk, 64));
                    if (lane == 0) wmax4[w] = m;
                }
                xbar();
                cur ^= 1;
            }
        }
        if (FWD) {
            *(float4*)&FA[n * 1024 + 4 * q] = make_float4(P0, P1, P2, P3);
            if (q == 0) FAe[n] = acc;
        } else {
            FB[n * 1024 + q]       = P0;
            FB[n * 1024 + q + 256] = P1;
            FB[n * 1024 + q + 512] = P2;
            FB[n * 1024 + q + 768] = P3;
            if (q == 0) FBe[n] = acc;
        }
    } else {
        // ---------------- CTC halves (log2 domain, per-lane depth-16 reg pipeline) ----------------
        float* abuf = &buf[0][0];                            // reuse [2][256] of buf
        const bool FWD = (role == 2);
        tcl[q] = max(ys_pad[n * 256 + q] - 1, 0);
        xbar();
        int mch = 0; bool val;
        if (FWD) {
            val = (q >= 1 && q < LMAX);
            if (val) {
                const int code = tcl[q] * 256 + tcl[q + 1] * 64 + tcl[q + 2] * 16
                               + tcl[q + 3] * 4 + tcl[q + 4];
                mch = code * 4 + tcl[q - 1];
            }
        } else {
            val = (q < LMAX - 1);            // move into position q+1
            if (val) {
                const int code = tcl[q + 1] * 256 + tcl[q + 2] * 64 + tcl[q + 3] * 16
                               + tcl[q + 4] * 4 + tcl[q + 5];
                mch = code * 4 + tcl[q];
            }
        }
        const int li = ys_lens[n] - 5;       // len - 1
        float a = FWD ? ((q == 0) ? 0.f : NEGF)
                      : ((q == li) ? 0.f : NEGF);
        abuf[q] = a;
        const unsigned short* eb = e16 + (size_t)(n * T_STEPS) * CG + mch;
        unsigned short pv[16];
        #pragma unroll
        for (int s = 0; s < 16; ++s) {
            const int row = FWD ? s : (511 - s);
            pv[s] = eb[(size_t)row * CG];
        }
        xbar();
        const float STAY2 = (2.0f - 3.0f) * L2E;
        int cur = 0;
        for (int t = 0; t < 256; t += 16) {
            #pragma unroll
            for (int u = 0; u < 16; ++u) {
                const float g2 = val ? __builtin_amdgcn_logf(h2f(pv[u])) : NEGF;
                int tn = t + u + 16; if (tn > 255) tn = 255;
                const int row = FWD ? tn : (511 - tn);
                pv[u] = eb[(size_t)row * CG];
                float nb;
                if (FWD) nb = (q > 0)   ? abuf[cur * 256 + q - 1] : NEGF;
                else     nb = (q < 255) ? abuf[cur * 256 + q + 1] : NEGF;
                const float st = a + STAY2;
                const float mv = nb + g2;
                const float mx = fmaxf(st, mv);
                const float mn = fminf(st, mv);
                a = mx + __builtin_amdgcn_logf(1.f + __builtin_amdgcn_exp2f(mn - mx));
                abuf[(cur ^ 1) * 256 + q] = a;
                xbar();
                cur ^= 1;
            }
        }
        if (FWD) CAL[n * 256 + q] = a;
        else     CBE[n * 256 + q] = a;
    }
}

// ---------------- combine + loss: out[n] = -((un - logZ)/len) ----------------
__global__ __launch_bounds__(256) void combine2_kernel(
    const float* __restrict__ FA, const float* __restrict__ FAe,
    const float* __restrict__ FB, const float* __restrict__ FBe,
    const float* __restrict__ CAL, const float* __restrict__ CBE,
    const int* __restrict__ ys_lens,
    float* __restrict__ out)
{
    __shared__ float red[256];
    __shared__ float lz;
    const int n = blockIdx.x;
    const int q = threadIdx.x;
    float s = 0.f;
    #pragma unroll
    for (int k = 0; k < 4; ++k)
        s += FA[n * 1024 + 4 * q + k] * FB[n * 1024 + 4 * q + k];
    red[q] = s; __syncthreads();
    for (int off = 128; off > 0; off >>= 1) {
        if (q < off) red[q] += red[q + off];
        __syncthreads();
    }
    if (q == 0) lz = FAe[n] + FBe[n] + __builtin_amdgcn_logf(red[0]);
    __syncthreads();
    const float x = CAL[n * 256 + q] + CBE[n * 256 + q];
    red[q] = x; __syncthreads();
    for (int off = 128; off > 0; off >>= 1) {
        if (q < off) red[q] = fmaxf(red[q], red[q + off]);
        __syncthreads();
    }
    const float m = red[0]; __syncthreads();
    red[q] = __builtin_amdgcn_exp2f(x - m); __syncthreads();
    for (int off = 128; off > 0; off >>= 1) {
        if (q < off) red[q] += red[q + off];
        __syncthreads();
    }
    if (q == 0) {
        const float un = m + __builtin_amdgcn_logf(red[0]);
        out[n] = -(LN2 * (un - lz) / (float)ys_lens[n]);
    }
}

// ---------------- fallback fused fwd on f32 interleaved scores (round-2, known-good) ----------------
__global__ __launch_bounds__(1024) void crf_fwd_kernel(
    const float* __restrict__ scores,
    const int* __restrict__ ys_pad,
    const int* __restrict__ ys_lens,
    float* __restrict__ ws)
{
    const int blk = blockIdx.x;
    const float STAY = 2.0f * L2E;
    if (blk < NB) {
        const int n = blk;
        const int s = threadIdx.x;
        __shared__ float buf[2][1024];
        __shared__ float red[1024];
        float alpha = 0.f;
        buf[0][s] = 0.f;
        const int j0 = s >> 2;
        const float* rowp = scores + (size_t)(n * T_STEPS) * CO + 5 * s + 1;
        float pm[4][4];
        #pragma unroll
        for (int u = 0; u < 4; ++u) {
            const float* r = rowp + (size_t)u * CO;
            pm[u][0] = r[0]; pm[u][1] = r[1]; pm[u][2] = r[2]; pm[u][3] = r[3];
        }
        __syncthreads();
        int cur = 0;
        for (int t = 0; t < T_STEPS; t += 4) {
            #pragma unroll
            for (int u = 0; u < 4; ++u) {
                const float m1 = pm[u][0], m2 = pm[u][1], m3 = pm[u][2], m4 = pm[u][3];
                int tp = t + u + 4; if (tp > T_STEPS - 1) tp = T_STEPS - 1;
                const float* r = rowp + (size_t)tp * CO;
                pm[u][0] = r[0]; pm[u][1] = r[1]; pm[u][2] = r[2]; pm[u][3] = r[3];
                const float b1 = buf[cur][j0];
                const float b2 = buf[cur][j0 + 256];
                const float b3 = buf[cur][j0 + 512];
                const float b4 = buf[cur][j0 + 768];
                const float a0 = alpha + STAY;
                const float a1 = fmaf(m1, L2E, b1);
                const float a2 = fmaf(m2, L2E, b2);
                const float a3 = fmaf(m3, L2E, b3);
                const float a4 = fmaf(m4, L2E, b4);
                const float mx = fmaxf(fmaxf(fmaxf(a0, a1), fmaxf(a2, a3)), a4);
                const float sum = __builtin_amdgcn_exp2f(a0 - mx) + __builtin_amdgcn_exp2f(a1 - mx)
                                + __builtin_amdgcn_exp2f(a2 - mx) + __builtin_amdgcn_exp2f(a3 - mx)
                                + __builtin_amdgcn_exp2f(a4 - mx);
                alpha = mx + __builtin_amdgcn_logf(sum);
                buf[cur ^ 1][s] = alpha;
                __syncthreads();
                cur ^= 1;
            }
        }
        red[s] = alpha;
        __syncthreads();
        for (int off = 512; off > 0; off >>= 1) {
            if (s < off) red[s] = fmaxf(red[s], red[s + off]);
            __syncthreads();
        }
        const float gmax = red[0];
        __syncthreads();
        red[s] = __builtin_amdgcn_exp2f(alpha - gmax);
        __syncthreads();
        for (int off = 512; off > 0; off >>= 1) {
            if (s < off) red[s] += red[s + off];
            __syncthreads();
        }
        if (s == 0) ws[n] = LN2 * (gmax + __builtin_amdgcn_logf(red[0]));
    } else {
        const int n = blk - NB;
        const int i = threadIdx.x;
        __shared__ float abuf[2][LMAX];
        __shared__ int tcl[256];
        if (i < 256) tcl[i] = max(ys_pad[n * 256 + i] - 1, 0);
        __syncthreads();
        int mch = -1;
        if (i >= 1 && i < LMAX) {
            const int code = tcl[i] * 256 + tcl[i + 1] * 64 + tcl[i + 2] * 16
                           + tcl[i + 3] * 4 + tcl[i + 4];
            mch = code * 5 + tcl[i - 1] + 1;
        }
        float alpha = (i == 0) ? 0.f : NEGF;
        if (i < LMAX) abuf[0][i] = alpha;
        const float* base = scores + (size_t)(n * T_STEPS) * CO;
        const size_t moff = (mch >= 0) ? (size_t)mch : 0;
        float pg[4];
        #pragma unroll
        for (int u = 0; u < 4; ++u) pg[u] = base[(size_t)u * CO + moff];
        __syncthreads();
        int cur = 0;
        for (int t = 0; t < T_STEPS; t += 4) {
            #pragma unroll
            for (int u = 0; u < 4; ++u) {
                const float g = pg[u];
                int tp = t + u + 4; if (tp > T_STEPS - 1) tp = T_STEPS - 1;
                pg[u] = base[(size_t)tp * CO + moff];
                if (i < LMAX) {
                    const float a_stay = alpha + STAY;
                    const float prev = (i > 0) ? abuf[cur][i - 1] : NEGF;
                    const float a_mv = (i > 0) ? fmaf(g, L2E, prev) : NEGF;
                    const float mx = fmaxf(a_stay, a_mv);
                    const float mn = fminf(a_stay, a_mv);
                    alpha = mx + __builtin_amdgcn_logf(1.f + __builtin_amdgcn_exp2f(mn - mx));
                    abuf[cur ^ 1][i] = alpha;
                }
                __syncthreads();
                cur ^= 1;
            }
        }
        if (i == ys_lens[n] - 5) ws[NB + n] = alpha * LN2;
    }
}

// ---------------- fallback loss ----------------
__global__ void crf_loss_kernel(const float* __restrict__ ws,
                                const int* __restrict__ ys_lens,
                                float* __restrict__ out)
{
    const int n = threadIdx.x;
    if (n < NB) {
        const float logz = ws[NB + n] - ws[n];
        out[n] = -(logz / (float)ys_lens[n]);
    }
}

extern "C" void kernel_launch(void* const* d_in, const int* in_sizes, int n_in,
                              void* d_out, int out_size, void* d_ws, size_t ws_size,
                              hipStream_t stream)
{
    const float* hs      = (const float*)d_in[0];
    const int*   ys_pad  = (const int*)d_in[2];
    const int*   ys_lens = (const int*)d_in[3];
    const float* W       = (const float*)d_in[4];
    const float* bias    = (const float*)d_in[5];
    float* out = (float*)d_out;
    float* ws  = (float*)d_ws;

    const size_t A_ELEMS = (size_t)8192 * 512;
    const size_t W_ELEMS = (size_t)4096 * 512;
    const size_t E_ELEMS = (size_t)8192 * 4096;
    const size_t X_FLOATS = (size_t)16 * 1024 * 2 + 32 + (size_t)16 * 256 * 2;
    const size_t NEED = 256 + (A_ELEMS + W_ELEMS + E_ELEMS) * 2 + X_FLOATS * 4;

    unsigned short* A16 = (unsigned short*)((char*)d_ws + 256);
    unsigned short* W16 = A16 + A_ELEMS;
    unsigned short* E16 = W16 + W_ELEMS;
    float* FA  = (float*)(E16 + E_ELEMS);
    float* FAe = FA + 16 * 1024;
    float* FB  = FAe + 16;
    float* FBe = FB + 16 * 1024;
    float* CAL = FBe + 16;
    float* CBE = CAL + 16 * 256;

    cvt_bf16_kernel<<<(int)(A_ELEMS / 4 / 256), 256, 0, stream>>>(hs, A16, (int)(A_ELEMS / 4));
    cvt_bf16_kernel<<<(int)(W_ELEMS / 4 / 256), 256, 0, stream>>>(W, W16, (int)(W_ELEMS / 4));
    dim3 grid(CG / 128, (NB * T_STEPS) / 128);

    if (ws_size >= NEED) {
        crf_gemm_bf16<true><<<grid, 256, 0, stream>>>(A16, W16, bias, out, E16);
        fb2_kernel<<<64, 256, 0, stream>>>(E16, ys_pad, ys_lens, FA, FAe, FB, FBe, CAL, CBE);
        combine2_kernel<<<16, 256, 0, stream>>>(FA, FAe, FB, FBe, CAL, CBE, ys_lens, out);
    } else {
        crf_gemm_bf16<false><<<grid, 256, 0, stream>>>(A16, W16, bias, out, nullptr);
        crf_fwd_kernel<<<2 * NB, 1024, 0, stream>>>(out + 16, ys_pad, ys_lens, ws);
        crf_loss_kernel<<<1, 64, 0, stream>>>(ws, ys_lens, out);
    }
}